// Round 18
// baseline (135.268 us; speedup 1.0000x reference)
//
#include <hip/hip_runtime.h>
#include <math.h>

// Problem constants: BS=8, FPS=64, PPF=1024, XC=64, K=64, YS=128
// N = 524288 points, T = 512 tiles (frames), batch = frame/64. CDF = 0.9
//
// Structure notes (post-mortems r11/r13/r15/r16): (a) fusing the 1024-thread
// tile phase with register-heavy phases fails (VGPR cap -> spill / VGPR=16
// serialization). (b) The score body compiles cleanly ONLY as a single-pass
// 256-thread kernel (r15/r11 allocator cliff). (c) Data-dependent break in
// the cumsum kills unroll -> serializes ~920 dependent LDS reads (+24us,
// r16). 4-kernel skeleton + single-pass score + unrolled cumsum is the
// validated optimum shape.

typedef __attribute__((ext_vector_type(8))) short short8v;  // 8 bf16 (4 VGPRs)
typedef __attribute__((ext_vector_type(4))) float f32x4;

__device__ __forceinline__ unsigned short bf16rne(float f) {
    unsigned u = __builtin_bit_cast(unsigned, f);
    return (unsigned short)((u + 0x7fffu + ((u >> 16) & 1u)) >> 16);
}
__device__ __forceinline__ float bf16f(unsigned short h) {
    unsigned u = ((unsigned)h) << 16;
    return __builtin_bit_cast(float, u);
}

// Fast tanh: tanh(z) = copysign((1-e)/(1+e), z), e = exp(-2|z|).
__device__ __forceinline__ float fast_tanh(float z) {
    float az = fabsf(z);
    float e  = __expf(-2.0f * az);
    float r  = (1.0f - e) * __builtin_amdgcn_rcpf(1.0f + e);
    return copysignf(r, z);
}

// ---------------------------------------------------------------- K1: prep = yk (8x64 GEMV) + one-time Wc 3-way bf16 split
__global__ __launch_bounds__(512) void prep_kernel(const float* __restrict__ y,
                                                   const float* __restrict__ Wy,
                                                   const float* __restrict__ Wc,
                                                   const float* __restrict__ bc,
                                                   const float* __restrict__ Wa,
                                                   short8v* __restrict__ wfrag,
                                                   float* __restrict__ pre,
                                                   float* __restrict__ waCopy) {
    __shared__ float yks[512];
    const int tid = threadIdx.x;          // 512 = 8 batches * 64 k
    {
        const int b = tid >> 6, k = tid & 63;
        const float* yrow = y + b * 128;
        const float* wrow = Wy + k * 128;
        float a0 = 0.f, a1 = 0.f, a2 = 0.f, a3 = 0.f;
#pragma unroll
        for (int j = 0; j < 128; j += 4) {
            a0 += yrow[j + 0] * wrow[j + 0];
            a1 += yrow[j + 1] * wrow[j + 1];
            a2 += yrow[j + 2] * wrow[j + 2];
            a3 += yrow[j + 3] * wrow[j + 3];
        }
        yks[tid] = (a0 + a1) + (a2 + a3);
    }
    __syncthreads();

    for (int f = tid; f < 1536; f += 512) {
        int ln = f & 63, t = f >> 6, kt = t & 3, pc = t >> 2;
        int cs = pc & 1, pr = pc >> 1;
        int k = kt * 16 + (ln & 15), c = cs * 32 + 8 * (ln >> 4);
        const float* wr = Wc + k * 64 + c;
        short8v o;
#pragma unroll
        for (int j = 0; j < 8; ++j) {
            float v = wr[j];
            unsigned short hb = bf16rne(v);
            if (pr == 0) { o[j] = (short)hb; continue; }
            float r1 = v - bf16f(hb);
            unsigned short mb = bf16rne(r1);
            if (pr == 1) { o[j] = (short)mb; continue; }
            float r2 = r1 - bf16f(mb);
            o[j] = (short)bf16rne(r2);
        }
        wfrag[f] = o;
    }
    pre[tid] = bc[tid & 63] + yks[tid];
    if (tid < 64) waCopy[tid] = Wa[tid];
}

// ---------------------------------------------------------------- K2: scores via bf16-split MFMA
// Round-18: sWf LDS tile REMOVED. The 24KB B-fragment region is shared by
// all blocks and L1-resident (32KB L1/CU); reading it direct from global
// (1KB coalesced per wave-load) drops LDS/block 25KB -> 512B, lifting HW
// residency 5 -> 8 blocks/CU at the unchanged 64-VGPR allocation — the
// latency hiding this kernel lacked (Occupancy 37%). Arithmetic unchanged.
// launch_bounds stays (256,5): the known-good allocator shape (2nd arg is
// a register-budget floor, not a residency cap).
// Layouts (m89/m91-verified C/D; standard CDNA A/B):
//   A: row=lane&15, k=8*(lane>>4)+j   B: col=lane&15, k=8*(lane>>4)+j
//   D: col=lane&15 (=k), row=(lane>>4)*4+reg (=point)
__global__ __launch_bounds__(256, 5) void score_kernel(const float* __restrict__ x,
                                                       const short8v* __restrict__ wfrag,
                                                       const float* __restrict__ pre,
                                                       const float* __restrict__ waCopy,
                                                       const float* __restrict__ ba,
                                                       float* __restrict__ scores) {
    __shared__ float sPre[64];
    __shared__ float sWaS[64];
    const int tid  = threadIdx.x;
    const int lane = tid & 63;
    const int wv   = tid >> 6;
    const int b    = blockIdx.x >> 9;              // 512 blocks per batch
    const int pbase = blockIdx.x * 128 + wv * 32;  // this wave's 32 points

    // ---- prefetch this wave's 32 x-rows (HBM latency overlaps pre-staging)
    const int prow0 = pbase + (lane & 15);
    const int cg = 8 * (lane >> 4);
    float4 u[2][2][2];                             // [ptile][cstep][half]
#pragma unroll
    for (int pt = 0; pt < 2; ++pt) {
        const float* xr = x + (long long)(prow0 + pt * 16) * 64;
#pragma unroll
        for (int cs = 0; cs < 2; ++cs) {
            const float4* xp4 = (const float4*)(xr + cs * 32 + cg);
            u[pt][cs][0] = xp4[0];
            u[pt][cs][1] = xp4[1];
        }
    }

    if (tid < 64) { sPre[tid] = pre[b * 64 + tid]; sWaS[tid] = waCopy[tid]; }
    __syncthreads();

    // ---- split x rows into A fragments (truncation split; exact residuals)
    short8v A[2][3][2];                            // [ptile][prec][cstep]
#pragma unroll
    for (int pt = 0; pt < 2; ++pt) {
#pragma unroll
        for (int cs = 0; cs < 2; ++cs) {
            float4 u0 = u[pt][cs][0], u1 = u[pt][cs][1];
            float v[8] = {u0.x, u0.y, u0.z, u0.w, u1.x, u1.y, u1.z, u1.w};
            short8v h, m, l;
#pragma unroll
            for (int j = 0; j < 8; ++j) {
                float vv = v[j];
                unsigned short hb = (unsigned short)(__builtin_bit_cast(unsigned, vv) >> 16);
                float r1 = vv - bf16f(hb);
                unsigned short mb = (unsigned short)(__builtin_bit_cast(unsigned, r1) >> 16);
                float r2 = r1 - bf16f(mb);
                unsigned short lb = (unsigned short)(__builtin_bit_cast(unsigned, r2) >> 16);
                h[j] = (short)hb; m[j] = (short)mb; l[j] = (short)lb;
            }
            A[pt][0][cs] = h; A[pt][1][cs] = m; A[pt][2][cs] = l;
        }
    }

    // ---- MFMA over 4 k-tiles, fused tanh/Wa epilogue; B direct from global
    f32x4 sacc[2] = {{0.f, 0.f, 0.f, 0.f}, {0.f, 0.f, 0.f, 0.f}};
    const float ba0 = ba[0];
    const int kcol = lane & 15;
#pragma unroll
    for (int kt = 0; kt < 4; ++kt) {
        short8v B[3][2];
#pragma unroll
        for (int pr = 0; pr < 3; ++pr)
#pragma unroll
            for (int cs = 0; cs < 2; ++cs)
                B[pr][cs] = wfrag[((pr * 2 + cs) * 4 + kt) * 64 + lane];
        const float prek = sPre[kt * 16 + kcol];
        const float wak = sWaS[kt * 16 + kcol];
#pragma unroll
        for (int pt = 0; pt < 2; ++pt) {
            f32x4 acc = {0.f, 0.f, 0.f, 0.f};
#pragma unroll
            for (int cs = 0; cs < 2; ++cs) {
                // smallest terms first: lh, hl, mm, mh, hm, hh
                acc = __builtin_amdgcn_mfma_f32_16x16x32_bf16(A[pt][2][cs], B[0][cs], acc, 0, 0, 0);
                acc = __builtin_amdgcn_mfma_f32_16x16x32_bf16(A[pt][0][cs], B[2][cs], acc, 0, 0, 0);
                acc = __builtin_amdgcn_mfma_f32_16x16x32_bf16(A[pt][1][cs], B[1][cs], acc, 0, 0, 0);
                acc = __builtin_amdgcn_mfma_f32_16x16x32_bf16(A[pt][1][cs], B[0][cs], acc, 0, 0, 0);
                acc = __builtin_amdgcn_mfma_f32_16x16x32_bf16(A[pt][0][cs], B[1][cs], acc, 0, 0, 0);
                acc = __builtin_amdgcn_mfma_f32_16x16x32_bf16(A[pt][0][cs], B[0][cs], acc, 0, 0, 0);
            }
#pragma unroll
            for (int r = 0; r < 4; ++r) {
                float z = acc[r] + prek;
                sacc[pt][r] += wak * fast_tanh(z);
            }
        }
    }

    // ---- reduce over k (16 lanes per group); float4 packed store per pt
#pragma unroll
    for (int pt = 0; pt < 2; ++pt) {
        float4 o;
#pragma unroll
        for (int r = 0; r < 4; ++r) {
            float v = sacc[pt][r];
            v += __shfl_xor(v, 1);
            v += __shfl_xor(v, 2);
            v += __shfl_xor(v, 4);
            v += __shfl_xor(v, 8);
            ((float*)&o)[r] = v + ba0;
        }
        if (kcol == 0)
            *(float4*)&scores[pbase + pt * 16 + (lane >> 4) * 4] = o;
    }
}

// ---------------------------------------------------------------- K3: per-tile softmax + stable-desc sort + cumsum + keep flags
// Register-resident bitonic: j<=32 stages via __shfl_xor (no LDS/barrier),
// j>=64 via LDS. Sort output bit-identical to the all-LDS version.
// Cumsum: full 1024-iter loop with #pragma unroll 8 — r16 showed a data-
// dependent break kills the unroll and serializes ~920 dependent LDS reads
// (+24us). Keep it branch-free so loads batch.
__global__ __launch_bounds__(1024) void tile_kernel(const float* __restrict__ scores,
                                                    int* __restrict__ flags,
                                                    int* __restrict__ keepcnt) {
    const int t = blockIdx.x, tid = threadIdx.x;
    __shared__ float sw[1024];
    __shared__ int   si[1024];
    __shared__ float red[16];
    __shared__ int   keep_s;

    const int lane = tid & 63, wid = tid >> 6;
    float s = scores[t * 1024 + tid];

    // max reduce
    float m = s;
#pragma unroll
    for (int o = 32; o; o >>= 1) m = fmaxf(m, __shfl_xor(m, o));
    if (lane == 0) red[wid] = m;
    __syncthreads();
    float mb = red[0];
#pragma unroll
    for (int q = 1; q < 16; ++q) mb = fmaxf(mb, red[q]);
    __syncthreads();    // red reused below

    float e = expf(s - mb);
    float su = e;
#pragma unroll
    for (int o = 32; o; o >>= 1) su += __shfl_xor(su, o);
    if (lane == 0) red[wid] = su;
    __syncthreads();
    float tot = 0.f;
#pragma unroll
    for (int q = 0; q < 16; ++q) tot += red[q];

    float w  = e / tot;    // my element (register-resident through the sort)
    int   idx = tid;

    // bitonic sort, descending by (w desc, idx asc)
    for (int kk = 2; kk <= 1024; kk <<= 1) {
        for (int j = kk >> 1; j > 0; j >>= 1) {
            bool lower = (tid & j) == 0;
            bool desc2 = (tid & kk) == 0;
            float wp; int ip;
            if (j >= 64) {
                sw[tid] = w; si[tid] = idx;
                __syncthreads();
                wp = sw[tid ^ j]; ip = si[tid ^ j];
                bool before = (w > wp) || (w == wp && idx < ip);
                bool keep = desc2 ? (before == lower) : (before != lower);
                if (!keep) { w = wp; idx = ip; }
                __syncthreads();
            } else {
                wp = __shfl_xor(w, j);
                ip = __shfl_xor(idx, j);
                bool before = (w > wp) || (w == wp && idx < ip);
                bool keep = desc2 ? (before == lower) : (before != lower);
                if (!keep) { w = wp; idx = ip; }
            }
        }
    }

    // publish sorted weights for the cumsum
    sw[tid] = w;
    __syncthreads();

    // sequential cumsum (bit-exact association), keep = #(csum<0.9)+1
    if (tid == 0) {
        float c = 0.f; int kp = 0;
#pragma unroll 8
        for (int q = 0; q < 1024; ++q) { c += sw[q]; if (c < 0.9f) ++kp; }
        keep_s = kp + 1;
        keepcnt[t] = kp + 1;
    }
    __syncthreads();

    // point idx (sorted position tid) kept iff tid < keep
    flags[t * 1024 + idx] = (tid < keep_s) ? 1 : 0;
}

// ---------------------------------------------------------------- K5: stream compaction, cooperative coalesced copy
// offsets folded in: each block computes its own base (= sum keepcnt[q<t])
// with a 64-lane x 8-entry integer scan (exact).
__global__ __launch_bounds__(1024) void compact_kernel(const float* __restrict__ x,
                                                       const int* __restrict__ locs,
                                                       const int* __restrict__ flags,
                                                       const int* __restrict__ keepcnt,
                                                       float* __restrict__ out,
                                                       int M) {
    const int t = blockIdx.x, tid = threadIdx.x;
    const long long gi = (long long)t * 1024 + tid;
    const int f = flags[gi];
    const int lane = tid & 63, wid = tid >> 6;

    __shared__ int wtot[16];
    __shared__ int woff[16];
    __shared__ int rowsrc[1024];
    __shared__ int nk_s;
    __shared__ int base_s;

    // ---- inline exclusive scan of keepcnt[0..t-1] (wave 0 only)
    if (wid == 0) {
        int s = 0;
#pragma unroll
        for (int j = 0; j < 8; ++j) {
            int q = lane * 8 + j;               // covers all 512 tiles
            int kc = keepcnt[q];
            if (q < t) s += kc;
        }
#pragma unroll
        for (int o = 32; o; o >>= 1) s += __shfl_xor(s, o);
        if (lane == 0) base_s = s;
    }

    unsigned long long ball = __ballot(f != 0);
    int wpre = __popcll(ball & (((unsigned long long)1 << lane) - 1ULL));
    if (lane == 63) wtot[wid] = wpre + f;
    __syncthreads();
    if (tid == 0) {
        int r = 0;
#pragma unroll
        for (int q = 0; q < 16; ++q) { woff[q] = r; r += wtot[q]; }
        nk_s = r;
    }
    __syncthreads();

    const int base = base_s;
    if (f) {
        const int local = woff[wid] + wpre;
        rowsrc[local] = tid;
        // locations (12 B/row, scattered — minor traffic)
        const long long pos = (long long)base + local;
        float* lout = out + (long long)M * 64 + pos * 3;
        lout[0] = (float)locs[gi * 3 + 0];
        lout[1] = (float)locs[gi * 3 + 1];
        lout[2] = (float)locs[gi * 3 + 2];
    }
    __syncthreads();

    const int nk = nk_s;
    const int rsub = tid >> 4;           // row within a 64-row pass
    const int col  = tid & 15;           // float4 index within row
    for (int r0 = 0; r0 < nk; r0 += 64) {
        const int rr = r0 + rsub;
        if (rr < nk) {
            const int srow = rowsrc[rr];
            const float4* src = (const float4*)(x + ((long long)t * 1024 + srow) * 64);
            float4* dst = (float4*)(out + (long long)(base + rr) * 64);
            dst[col] = src[col];
        }
    }
}

// ----------------------------------------------------------------
extern "C" void kernel_launch(void* const* d_in, const int* in_sizes, int n_in,
                              void* d_out, int out_size, void* d_ws, size_t ws_size,
                              hipStream_t stream) {
    const float* x    = (const float*)d_in[0];
    const int*   locs = (const int*)d_in[1];
    const float* y    = (const float*)d_in[2];
    const float* Wc   = (const float*)d_in[3];
    const float* bc   = (const float*)d_in[4];
    const float* Wy   = (const float*)d_in[5];
    const float* Wa   = (const float*)d_in[6];
    const float* ba   = (const float*)d_in[7];

    const int N = in_sizes[0] / 64;       // 524288
    const int T = N / 1024;               // 512
    const int M = out_size / 67;          // kept points (64 x-cols + 3 loc-cols)

    float* ws      = (float*)d_ws;
    float* scores  = ws + 512;                // N floats
    int*   flags   = (int*)(ws + 512 + N);    // N ints
    int*   keepcnt = flags + N;               // T ints
    // 16B-aligned tail: 512+2N+2T floats = 4,200,448 bytes, /16 exact
    short8v* wfrag = (short8v*)(ws + 512 + 2 * N + 2 * T);  // 1536 * 16 B
    float* pre     = ws + 512 + 2 * N + 2 * T + 6144;       // 512 floats
    float* waCopy  = pre + 512;                             // 64 floats

    prep_kernel<<<1, 512, 0, stream>>>(y, Wy, Wc, bc, Wa, wfrag, pre, waCopy);
    score_kernel<<<N / 128, 256, 0, stream>>>(x, wfrag, pre, waCopy, ba, scores);
    tile_kernel<<<T, 1024, 0, stream>>>(scores, flags, keepcnt);
    compact_kernel<<<T, 1024, 0, stream>>>(x, locs, flags, keepcnt, (float*)d_out, M);
}

// Round 19
// 130.035 us; speedup vs baseline: 1.0402x; 1.0402x over previous
//
#include <hip/hip_runtime.h>
#include <math.h>

// Problem constants: BS=8, FPS=64, PPF=1024, XC=64, K=64, YS=128
// N = 524288 points, T = 512 tiles (frames), batch = frame/64. CDF = 0.9
//
// Validated-plateau structure (post-mortems r11/r13/r15/r16/r18):
// (a) fusing the 1024-thread tile phase with register-heavy phases fails
//     (VGPR cap -> spill / VGPR=16 serialization).
// (b) The score body compiles cleanly ONLY as a single-pass 256-thread
//     kernel (r15/r11 allocator cliff: 48 VGPR + 486MB scratch FETCH).
// (c) Data-dependent break in the cumsum kills unroll -> serializes ~920
//     dependent LDS reads (+24us, r16).
// (d) sWf MUST stay in LDS: direct-global B reads contend on the VMEM pipe
//     with x loads (+5us, r18) despite lower LDS/occupancy headroom.
// 4-kernel skeleton + single-pass score + LDS sWf + unrolled cumsum.

typedef __attribute__((ext_vector_type(8))) short short8v;  // 8 bf16 (4 VGPRs)
typedef __attribute__((ext_vector_type(4))) float f32x4;

__device__ __forceinline__ unsigned short bf16rne(float f) {
    unsigned u = __builtin_bit_cast(unsigned, f);
    return (unsigned short)((u + 0x7fffu + ((u >> 16) & 1u)) >> 16);
}
__device__ __forceinline__ float bf16f(unsigned short h) {
    unsigned u = ((unsigned)h) << 16;
    return __builtin_bit_cast(float, u);
}

// Fast tanh: tanh(z) = copysign((1-e)/(1+e), z), e = exp(-2|z|).
__device__ __forceinline__ float fast_tanh(float z) {
    float az = fabsf(z);
    float e  = __expf(-2.0f * az);
    float r  = (1.0f - e) * __builtin_amdgcn_rcpf(1.0f + e);
    return copysignf(r, z);
}

// ---------------------------------------------------------------- K1: prep = yk (8x64 GEMV) + one-time Wc 3-way bf16 split
__global__ __launch_bounds__(512) void prep_kernel(const float* __restrict__ y,
                                                   const float* __restrict__ Wy,
                                                   const float* __restrict__ Wc,
                                                   const float* __restrict__ bc,
                                                   const float* __restrict__ Wa,
                                                   short8v* __restrict__ wfrag,
                                                   float* __restrict__ pre,
                                                   float* __restrict__ waCopy) {
    __shared__ float yks[512];
    const int tid = threadIdx.x;          // 512 = 8 batches * 64 k
    {
        const int b = tid >> 6, k = tid & 63;
        const float* yrow = y + b * 128;
        const float* wrow = Wy + k * 128;
        float a0 = 0.f, a1 = 0.f, a2 = 0.f, a3 = 0.f;
#pragma unroll
        for (int j = 0; j < 128; j += 4) {
            a0 += yrow[j + 0] * wrow[j + 0];
            a1 += yrow[j + 1] * wrow[j + 1];
            a2 += yrow[j + 2] * wrow[j + 2];
            a3 += yrow[j + 3] * wrow[j + 3];
        }
        yks[tid] = (a0 + a1) + (a2 + a3);
    }
    __syncthreads();

    for (int f = tid; f < 1536; f += 512) {
        int ln = f & 63, t = f >> 6, kt = t & 3, pc = t >> 2;
        int cs = pc & 1, pr = pc >> 1;
        int k = kt * 16 + (ln & 15), c = cs * 32 + 8 * (ln >> 4);
        const float* wr = Wc + k * 64 + c;
        short8v o;
#pragma unroll
        for (int j = 0; j < 8; ++j) {
            float v = wr[j];
            unsigned short hb = bf16rne(v);
            if (pr == 0) { o[j] = (short)hb; continue; }
            float r1 = v - bf16f(hb);
            unsigned short mb = bf16rne(r1);
            if (pr == 1) { o[j] = (short)mb; continue; }
            float r2 = r1 - bf16f(mb);
            o[j] = (short)bf16rne(r2);
        }
        wfrag[f] = o;
    }
    pre[tid] = bc[tid & 63] + yks[tid];
    if (tid < 64) waCopy[tid] = Wa[tid];
}

// ---------------------------------------------------------------- K2: scores via bf16-split MFMA
// EXACT round-17 body (single pass, grid 4096, (256,5), LDS sWf, validated
// 64-VGPR no-spill codegen, FETCH ~66MB). Do NOT wrap in loops / resize
// block / drop the LDS tile (r15/r11/r18 regressions).
// Layouts (m89/m91-verified C/D; standard CDNA A/B):
//   A: row=lane&15, k=8*(lane>>4)+j   B: col=lane&15, k=8*(lane>>4)+j
//   D: col=lane&15 (=k), row=(lane>>4)*4+reg (=point)
__global__ __launch_bounds__(256, 5) void score_kernel(const float* __restrict__ x,
                                                       const short8v* __restrict__ wfrag,
                                                       const float* __restrict__ pre,
                                                       const float* __restrict__ waCopy,
                                                       const float* __restrict__ ba,
                                                       float* __restrict__ scores) {
    __shared__ short8v sWf[1536];   // [prec3][cstep2][ktile4][lane64], 24 KB
    __shared__ float sPre[64];
    __shared__ float sWaS[64];
    const int tid  = threadIdx.x;
    const int lane = tid & 63;
    const int wv   = tid >> 6;
    const int b    = blockIdx.x >> 9;              // 512 blocks per batch
    const int pbase = blockIdx.x * 128 + wv * 32;  // this wave's 32 points

    // ---- prefetch this wave's 32 x-rows (HBM latency overlaps staging)
    const int prow0 = pbase + (lane & 15);
    const int cg = 8 * (lane >> 4);
    float4 u[2][2][2];                             // [ptile][cstep][half]
#pragma unroll
    for (int pt = 0; pt < 2; ++pt) {
        const float* xr = x + (long long)(prow0 + pt * 16) * 64;
#pragma unroll
        for (int cs = 0; cs < 2; ++cs) {
            const float4* xp4 = (const float4*)(xr + cs * 32 + cg);
            u[pt][cs][0] = xp4[0];
            u[pt][cs][1] = xp4[1];
        }
    }

    // ---- stage pre-split Wc fragments: plain 16B vector copy
    for (int f = tid; f < 1536; f += 256) sWf[f] = wfrag[f];
    if (tid < 64) { sPre[tid] = pre[b * 64 + tid]; sWaS[tid] = waCopy[tid]; }
    __syncthreads();

    // ---- split x rows into A fragments (truncation split; exact residuals)
    short8v A[2][3][2];                            // [ptile][prec][cstep]
#pragma unroll
    for (int pt = 0; pt < 2; ++pt) {
#pragma unroll
        for (int cs = 0; cs < 2; ++cs) {
            float4 u0 = u[pt][cs][0], u1 = u[pt][cs][1];
            float v[8] = {u0.x, u0.y, u0.z, u0.w, u1.x, u1.y, u1.z, u1.w};
            short8v h, m, l;
#pragma unroll
            for (int j = 0; j < 8; ++j) {
                float vv = v[j];
                unsigned short hb = (unsigned short)(__builtin_bit_cast(unsigned, vv) >> 16);
                float r1 = vv - bf16f(hb);
                unsigned short mb = (unsigned short)(__builtin_bit_cast(unsigned, r1) >> 16);
                float r2 = r1 - bf16f(mb);
                unsigned short lb = (unsigned short)(__builtin_bit_cast(unsigned, r2) >> 16);
                h[j] = (short)hb; m[j] = (short)mb; l[j] = (short)lb;
            }
            A[pt][0][cs] = h; A[pt][1][cs] = m; A[pt][2][cs] = l;
        }
    }

    // ---- MFMA over 4 k-tiles, fused tanh/Wa epilogue
    f32x4 sacc[2] = {{0.f, 0.f, 0.f, 0.f}, {0.f, 0.f, 0.f, 0.f}};
    const float ba0 = ba[0];
    const int kcol = lane & 15;
#pragma unroll
    for (int kt = 0; kt < 4; ++kt) {
        short8v B[3][2];
#pragma unroll
        for (int pr = 0; pr < 3; ++pr)
#pragma unroll
            for (int cs = 0; cs < 2; ++cs)
                B[pr][cs] = sWf[((pr * 2 + cs) * 4 + kt) * 64 + lane];
        const float prek = sPre[kt * 16 + kcol];
        const float wak = sWaS[kt * 16 + kcol];
#pragma unroll
        for (int pt = 0; pt < 2; ++pt) {
            f32x4 acc = {0.f, 0.f, 0.f, 0.f};
#pragma unroll
            for (int cs = 0; cs < 2; ++cs) {
                // smallest terms first: lh, hl, mm, mh, hm, hh
                acc = __builtin_amdgcn_mfma_f32_16x16x32_bf16(A[pt][2][cs], B[0][cs], acc, 0, 0, 0);
                acc = __builtin_amdgcn_mfma_f32_16x16x32_bf16(A[pt][0][cs], B[2][cs], acc, 0, 0, 0);
                acc = __builtin_amdgcn_mfma_f32_16x16x32_bf16(A[pt][1][cs], B[1][cs], acc, 0, 0, 0);
                acc = __builtin_amdgcn_mfma_f32_16x16x32_bf16(A[pt][1][cs], B[0][cs], acc, 0, 0, 0);
                acc = __builtin_amdgcn_mfma_f32_16x16x32_bf16(A[pt][0][cs], B[1][cs], acc, 0, 0, 0);
                acc = __builtin_amdgcn_mfma_f32_16x16x32_bf16(A[pt][0][cs], B[0][cs], acc, 0, 0, 0);
            }
#pragma unroll
            for (int r = 0; r < 4; ++r) {
                float z = acc[r] + prek;
                sacc[pt][r] += wak * fast_tanh(z);
            }
        }
    }

    // ---- reduce over k (16 lanes per group); float4 packed store per pt
#pragma unroll
    for (int pt = 0; pt < 2; ++pt) {
        float4 o;
#pragma unroll
        for (int r = 0; r < 4; ++r) {
            float v = sacc[pt][r];
            v += __shfl_xor(v, 1);
            v += __shfl_xor(v, 2);
            v += __shfl_xor(v, 4);
            v += __shfl_xor(v, 8);
            ((float*)&o)[r] = v + ba0;
        }
        if (kcol == 0)
            *(float4*)&scores[pbase + pt * 16 + (lane >> 4) * 4] = o;
    }
}

// ---------------------------------------------------------------- K3: per-tile softmax + stable-desc sort + cumsum + keep flags
// Register-resident bitonic: j<=32 stages via __shfl_xor (no LDS/barrier),
// j>=64 via LDS. Sort output bit-identical to the all-LDS version.
// Cumsum: full 1024-iter loop with #pragma unroll 8 (branch-free; r16).
__global__ __launch_bounds__(1024) void tile_kernel(const float* __restrict__ scores,
                                                    int* __restrict__ flags,
                                                    int* __restrict__ keepcnt) {
    const int t = blockIdx.x, tid = threadIdx.x;
    __shared__ float sw[1024];
    __shared__ int   si[1024];
    __shared__ float red[16];
    __shared__ int   keep_s;

    const int lane = tid & 63, wid = tid >> 6;
    float s = scores[t * 1024 + tid];

    // max reduce
    float m = s;
#pragma unroll
    for (int o = 32; o; o >>= 1) m = fmaxf(m, __shfl_xor(m, o));
    if (lane == 0) red[wid] = m;
    __syncthreads();
    float mb = red[0];
#pragma unroll
    for (int q = 1; q < 16; ++q) mb = fmaxf(mb, red[q]);
    __syncthreads();    // red reused below

    float e = expf(s - mb);
    float su = e;
#pragma unroll
    for (int o = 32; o; o >>= 1) su += __shfl_xor(su, o);
    if (lane == 0) red[wid] = su;
    __syncthreads();
    float tot = 0.f;
#pragma unroll
    for (int q = 0; q < 16; ++q) tot += red[q];

    float w  = e / tot;    // my element (register-resident through the sort)
    int   idx = tid;

    // bitonic sort, descending by (w desc, idx asc)
    for (int kk = 2; kk <= 1024; kk <<= 1) {
        for (int j = kk >> 1; j > 0; j >>= 1) {
            bool lower = (tid & j) == 0;
            bool desc2 = (tid & kk) == 0;
            float wp; int ip;
            if (j >= 64) {
                sw[tid] = w; si[tid] = idx;
                __syncthreads();
                wp = sw[tid ^ j]; ip = si[tid ^ j];
                bool before = (w > wp) || (w == wp && idx < ip);
                bool keep = desc2 ? (before == lower) : (before != lower);
                if (!keep) { w = wp; idx = ip; }
                __syncthreads();
            } else {
                wp = __shfl_xor(w, j);
                ip = __shfl_xor(idx, j);
                bool before = (w > wp) || (w == wp && idx < ip);
                bool keep = desc2 ? (before == lower) : (before != lower);
                if (!keep) { w = wp; idx = ip; }
            }
        }
    }

    // publish sorted weights for the cumsum
    sw[tid] = w;
    __syncthreads();

    // sequential cumsum (bit-exact association), keep = #(csum<0.9)+1
    if (tid == 0) {
        float c = 0.f; int kp = 0;
#pragma unroll 8
        for (int q = 0; q < 1024; ++q) { c += sw[q]; if (c < 0.9f) ++kp; }
        keep_s = kp + 1;
        keepcnt[t] = kp + 1;
    }
    __syncthreads();

    // point idx (sorted position tid) kept iff tid < keep
    flags[t * 1024 + idx] = (tid < keep_s) ? 1 : 0;
}

// ---------------------------------------------------------------- K5: stream compaction, cooperative coalesced copy
// offsets folded in: each block computes its own base (= sum keepcnt[q<t])
// with a 64-lane x 8-entry integer scan (exact).
__global__ __launch_bounds__(1024) void compact_kernel(const float* __restrict__ x,
                                                       const int* __restrict__ locs,
                                                       const int* __restrict__ flags,
                                                       const int* __restrict__ keepcnt,
                                                       float* __restrict__ out,
                                                       int M) {
    const int t = blockIdx.x, tid = threadIdx.x;
    const long long gi = (long long)t * 1024 + tid;
    const int f = flags[gi];
    const int lane = tid & 63, wid = tid >> 6;

    __shared__ int wtot[16];
    __shared__ int woff[16];
    __shared__ int rowsrc[1024];
    __shared__ int nk_s;
    __shared__ int base_s;

    // ---- inline exclusive scan of keepcnt[0..t-1] (wave 0 only)
    if (wid == 0) {
        int s = 0;
#pragma unroll
        for (int j = 0; j < 8; ++j) {
            int q = lane * 8 + j;               // covers all 512 tiles
            int kc = keepcnt[q];
            if (q < t) s += kc;
        }
#pragma unroll
        for (int o = 32; o; o >>= 1) s += __shfl_xor(s, o);
        if (lane == 0) base_s = s;
    }

    unsigned long long ball = __ballot(f != 0);
    int wpre = __popcll(ball & (((unsigned long long)1 << lane) - 1ULL));
    if (lane == 63) wtot[wid] = wpre + f;
    __syncthreads();
    if (tid == 0) {
        int r = 0;
#pragma unroll
        for (int q = 0; q < 16; ++q) { woff[q] = r; r += wtot[q]; }
        nk_s = r;
    }
    __syncthreads();

    const int base = base_s;
    if (f) {
        const int local = woff[wid] + wpre;
        rowsrc[local] = tid;
        // locations (12 B/row, scattered — minor traffic)
        const long long pos = (long long)base + local;
        float* lout = out + (long long)M * 64 + pos * 3;
        lout[0] = (float)locs[gi * 3 + 0];
        lout[1] = (float)locs[gi * 3 + 1];
        lout[2] = (float)locs[gi * 3 + 2];
    }
    __syncthreads();

    const int nk = nk_s;
    const int rsub = tid >> 4;           // row within a 64-row pass
    const int col  = tid & 15;           // float4 index within row
    for (int r0 = 0; r0 < nk; r0 += 64) {
        const int rr = r0 + rsub;
        if (rr < nk) {
            const int srow = rowsrc[rr];
            const float4* src = (const float4*)(x + ((long long)t * 1024 + srow) * 64);
            float4* dst = (float4*)(out + (long long)(base + rr) * 64);
            dst[col] = src[col];
        }
    }
}

// ----------------------------------------------------------------
extern "C" void kernel_launch(void* const* d_in, const int* in_sizes, int n_in,
                              void* d_out, int out_size, void* d_ws, size_t ws_size,
                              hipStream_t stream) {
    const float* x    = (const float*)d_in[0];
    const int*   locs = (const int*)d_in[1];
    const float* y    = (const float*)d_in[2];
    const float* Wc   = (const float*)d_in[3];
    const float* bc   = (const float*)d_in[4];
    const float* Wy   = (const float*)d_in[5];
    const float* Wa   = (const float*)d_in[6];
    const float* ba   = (const float*)d_in[7];

    const int N = in_sizes[0] / 64;       // 524288
    const int T = N / 1024;               // 512
    const int M = out_size / 67;          // kept points (64 x-cols + 3 loc-cols)

    float* ws      = (float*)d_ws;
    float* scores  = ws + 512;                // N floats
    int*   flags   = (int*)(ws + 512 + N);    // N ints
    int*   keepcnt = flags + N;               // T ints
    // 16B-aligned tail: 512+2N+2T floats = 4,200,448 bytes, /16 exact
    short8v* wfrag = (short8v*)(ws + 512 + 2 * N + 2 * T);  // 1536 * 16 B
    float* pre     = ws + 512 + 2 * N + 2 * T + 6144;       // 512 floats
    float* waCopy  = pre + 512;                             // 64 floats

    prep_kernel<<<1, 512, 0, stream>>>(y, Wy, Wc, bc, Wa, wfrag, pre, waCopy);
    score_kernel<<<N / 128, 256, 0, stream>>>(x, wfrag, pre, waCopy, ba, scores);
    tile_kernel<<<T, 1024, 0, stream>>>(scores, flags, keepcnt);
    compact_kernel<<<T, 1024, 0, stream>>>(x, locs, flags, keepcnt, (float*)d_out, M);
}